// Round 12
// baseline (285.575 us; speedup 1.0000x reference)
//
#include <hip/hip_runtime.h>
#include <math.h>

#define B      2048
#define NRELS  512
#define FEAT   300
#define LAT    512

// task table (topological order)
#define T_FC1  0
#define T_QI1  160
#define T_MULS 224
#define T_QI2  736
#define T_FC3  800
#define T_QZ1  960
#define T_FC4  1216
#define T_QZ2  1376
#define T_CSL  1632
#define NTASK  2144
#define PGRID  512

// flag indices (each counter on its own 64B line: flg + idx*16)
#define F_FC1  0     // [32]
#define F_MULS 32    // [32]
#define F_FC3  64    // [32]
#define F_QZ1  96    // [32]
#define F_QZ2  128   // [32]
#define F_QI1  160   // [8]
#define F_QI2A 168   // qi2 all-done
#define F_CSLD 169   // csl done
#define NFLAGW (170 * 16)

typedef __attribute__((ext_vector_type(8))) short short8;
typedef __attribute__((ext_vector_type(4))) float f32x4;

__device__ inline short f2bf(float f) {
    union { float f; unsigned u; } v; v.f = f;
    unsigned u = v.u;
    u += 0x7fffu + ((u >> 16) & 1u);   // RNE
    return (short)(u >> 16);
}

// ================= weight descriptors (transpose tiles) =================
struct WDesc { const float* src; short* dst; int K, N, Kpad, Npad, ilv, ilvoff, tstart, tk; };
struct WPack { WDesc d[9]; };

struct Args {
    const float* logits; const int* rels; const float* rel_dict;
    const float* fc1_b; const float* mu_b; const float* ls_b;
    const float* fc3_b; const float* fc4_b;
    const float* qi1_b; const float* qi2_b; const float* qz1_b; const float* qz2_b;
    const float* eps1;  const float* eps2;
    float* out; float* zp;
    float* acc;          // [0]=kl [1]=recon [2]=csl
    unsigned* flg;
    int* top_idx; int* dis_idx;
    short* Rb; short* Ehb; float* E;
    short* xcat; float* xf;
    short* h1; short* zcat; short* zb; short* h3; short* t1;
    const short* w_qi1t; const short* w_qi2t; const short* w_fc1t; const short* w_mulst;
    const short* w_fc3t; const short* w_fc4t; const short* w_qz1t; const short* w_qz2t;
    WPack wp;
};

// ================= DISPATCH 1: prep (topk/gather | gather_R | transpose | zeros) ====
__global__ __launch_bounds__(256) void prep(Args g)
{
    __shared__ float T[64][65];
    const int bid = blockIdx.x;
    if (bid < 512) {
        int lane = threadIdx.x & 63;
        int row  = bid * 4 + (threadIdx.x >> 6);
        const float* pl = g.logits + (size_t)row * NRELS;
        float v[8];
#pragma unroll
        for (int j = 0; j < 8; ++j) v[j] = pl[j * 64 + lane];
        float w[8];
#pragma unroll
        for (int j = 0; j < 8; ++j) w[j] = v[j];
        for (int t = 0; t < 20; ++t) {
            float bv = __builtin_inff(); int bi = 0x7fffffff;
#pragma unroll
            for (int j = 0; j < 8; ++j) {
                int idx = j * 64 + lane;
                if (w[j] < bv || (w[j] == bv && idx < bi)) { bv = w[j]; bi = idx; }
            }
#pragma unroll
            for (int off = 32; off >= 1; off >>= 1) {
                float ov = __shfl_xor(bv, off);
                int   oi = __shfl_xor(bi, off);
                if (ov < bv || (ov == bv && oi < bi)) { bv = ov; bi = oi; }
            }
            if ((bi & 63) == lane) w[bi >> 6] = __builtin_inff();
            if (lane == 0) g.dis_idx[row * 20 + t] = bi;
        }
        int t3[3];
#pragma unroll
        for (int j = 0; j < 8; ++j) w[j] = v[j];
        for (int t = 0; t < 3; ++t) {
            float bv = -__builtin_inff(); int bi = 0x7fffffff;
#pragma unroll
            for (int j = 0; j < 8; ++j) {
                int idx = j * 64 + lane;
                if (w[j] > bv || (w[j] == bv && idx < bi)) { bv = w[j]; bi = idx; }
            }
#pragma unroll
            for (int off = 32; off >= 1; off >>= 1) {
                float ov = __shfl_xor(bv, off);
                int   oi = __shfl_xor(bi, off);
                if (ov > bv || (ov == bv && oi < bi)) { bv = ov; bi = oi; }
            }
            if ((bi & 63) == lane) w[bi >> 6] = -__builtin_inff();
            t3[t] = bi;
        }
        if (lane == 0) g.top_idx[row] = t3[0];
        int i0 = g.rels[2 * t3[0] + 1];
        int i1 = g.rels[2 * t3[1] + 1];
        int i2 = g.rels[2 * t3[2] + 1];
        const float* r0 = g.rel_dict + (size_t)i0 * FEAT;
        const float* r1 = g.rel_dict + (size_t)i1 * FEAT;
        const float* r2 = g.rel_dict + (size_t)i2 * FEAT;
        short* xd  = g.xcat + (size_t)row * 640;
        short* zd  = g.zcat + (size_t)row * 832;
        float* xfd = g.xf   + (size_t)row * 300;
        for (int c = lane; c < FEAT; c += 64) {
            float a = r0[c];
            float x = a * r1[c] * r2[c];
            xd[c]       = f2bf(x);
            xd[300 + c] = f2bf(a);
            zd[512 + c] = f2bf(a);
            xfd[c]      = x;
        }
        if (lane < 40) xd[600 + lane] = 0;
        if (lane < 20) zd[812 + lane] = 0;
    } else if (bid < 640) {
        int lane = threadIdx.x & 63;
        int j = (bid - 512) * 4 + (threadIdx.x >> 6);
        int id = g.rels[2 * j + 1];
        const float* src = g.rel_dict + (size_t)id * FEAT;
        for (int c = lane; c < 320; c += 64)
            g.Rb[(size_t)j * 320 + c] = (c < FEAT) ? f2bf(src[c]) : (short)0;
    } else if (bid < 1092) {
        // coalesced weight transpose: 64x64 LDS tile
        int uu = bid - 640;   // 0..451
        int di = 0;
#pragma unroll
        for (int q = 1; q < 9; ++q) if (uu >= g.wp.d[q].tstart) di = q;
        WDesc w = g.wp.d[di];
        int r  = uu - w.tstart;
        int kt = r % w.tk;
        int nt = r / w.tk;
        int k0 = kt * 64, n0 = nt * 64;
        {
            int kk = threadIdx.x >> 2;
            int c0 = (threadIdx.x & 3) * 16;
            int gk = k0 + kk;
            const float* srow = w.src + (size_t)gk * w.N;
            bool kin = gk < w.K;
#pragma unroll
            for (int j = 0; j < 16; ++j) {
                int gn = n0 + c0 + j;
                T[kk][c0 + j] = (kin && gn < w.N) ? srow[gn] : 0.f;
            }
        }
        __syncthreads();
        {
            int nn = threadIdx.x >> 2;
            int c0 = (threadIdx.x & 3) * 16;
            int ns = n0 + nn;
            int nd = w.ilv ? (((ns >> 5) << 6) + w.ilvoff + (ns & 31)) : ns;
            short* drow = w.dst + (size_t)nd * w.Kpad + k0;
#pragma unroll
            for (int j = 0; j < 16; ++j)
                drow[c0 + j] = f2bf(T[c0 + j][nn]);
        }
    } else {
        // zero z_rel row 0 + loss acc + all flags
        g.out[2 + threadIdx.x]       = 0.f;
        g.out[2 + 256 + threadIdx.x] = 0.f;
        if (threadIdx.x < 4) ((unsigned*)g.acc)[threadIdx.x] = 0u;
        for (int i = threadIdx.x; i < NFLAGW; i += 256) g.flg[i] = 0u;
    }
}

// ================= MFMA GEMM core (64x64 tile, BK=64, reg prefetch) =================
// MODE: 0 = store bf16, 1 = store f32, 2 = fc4 sigmoid+recon fuse, 3 = mu/ls sample fuse
template<int ACT, int MODE>   // ACT: 0 none, 1 relu, 2 leaky0.2, 3 sigmoid
__device__ __attribute__((always_inline)) void gemm_core(
    short (&As)[64][72], short (&Bs)[64][72],
    int bx, int by,
    const short* __restrict__ A, const short* __restrict__ Bt,
    const float* __restrict__ bias, const float* __restrict__ bias2,
    void* __restrict__ Cv, int Nreal, int Kpad, int ldc,
    const float* __restrict__ aux0, const float* __restrict__ aux1,
    short* __restrict__ z0, short* __restrict__ z1,
    float* __restrict__ accv)
{
    const int wave = threadIdx.x >> 6;
    const int lane = threadIdx.x & 63;
    const int row0 = by * 64;
    const int col0 = bx * 64;

    const int srow = threadIdx.x >> 3;
    const int sk   = (threadIdx.x & 7) * 8;
    const short* Ap0 = A  + (size_t)(row0 + srow)      * Kpad + sk;
    const short* Ap1 = A  + (size_t)(row0 + srow + 32) * Kpad + sk;
    const short* Bp0 = Bt + (size_t)(col0 + srow)      * Kpad + sk;
    const short* Bp1 = Bt + (size_t)(col0 + srow + 32) * Kpad + sk;

    const int frow = lane & 15;
    const int fk   = (lane >> 4) * 8;

    f32x4 acc0 = {0,0,0,0}, acc1 = {0,0,0,0}, acc2 = {0,0,0,0}, acc3 = {0,0,0,0};

    short8 a0 = *(const short8*)Ap0;
    short8 a1 = *(const short8*)Ap1;
    short8 b0 = *(const short8*)Bp0;
    short8 b1 = *(const short8*)Bp1;

    for (int k0 = 0; k0 < Kpad; k0 += 64) {
        *(short8*)&As[srow][sk]      = a0;
        *(short8*)&As[srow + 32][sk] = a1;
        *(short8*)&Bs[srow][sk]      = b0;
        *(short8*)&Bs[srow + 32][sk] = b1;
        __syncthreads();
        int kn = k0 + 64;
        if (kn < Kpad) {
            a0 = *(const short8*)(Ap0 + kn);
            a1 = *(const short8*)(Ap1 + kn);
            b0 = *(const short8*)(Bp0 + kn);
            b1 = *(const short8*)(Bp1 + kn);
        }
#pragma unroll
        for (int kk = 0; kk < 2; ++kk) {
            short8 af  = *(const short8*)&As[wave * 16 + frow][fk + kk * 32];
            short8 bf0 = *(const short8*)&Bs[ 0 + frow][fk + kk * 32];
            short8 bf1 = *(const short8*)&Bs[16 + frow][fk + kk * 32];
            short8 bf2 = *(const short8*)&Bs[32 + frow][fk + kk * 32];
            short8 bf3 = *(const short8*)&Bs[48 + frow][fk + kk * 32];
            acc0 = __builtin_amdgcn_mfma_f32_16x16x32_bf16(af, bf0, acc0, 0, 0, 0);
            acc1 = __builtin_amdgcn_mfma_f32_16x16x32_bf16(af, bf1, acc1, 0, 0, 0);
            acc2 = __builtin_amdgcn_mfma_f32_16x16x32_bf16(af, bf2, acc2, 0, 0, 0);
            acc3 = __builtin_amdgcn_mfma_f32_16x16x32_bf16(af, bf3, acc3, 0, 0, 0);
        }
        __syncthreads();
    }

    const int orow = row0 + wave * 16 + (lane >> 4) * 4;
    f32x4 accs[4] = {acc0, acc1, acc2, acc3};

    if (MODE == 3) {
        float kls = 0.f;
#pragma unroll
        for (int n0 = 0; n0 < 2; ++n0) {
            int zc = bx * 32 + n0 * 16 + frow;
            float bmu = bias[zc];
            float bls = bias2[zc];
#pragma unroll
            for (int j = 0; j < 4; ++j) {
                int row = orow + j;
                float m = accs[n0][j]     + bmu;
                float l = accs[n0 + 2][j] + bls;
                float s = expf(l);
                size_t ei = (size_t)row * 512 + zc;
                z0[(size_t)row * 832 + zc] = f2bf(m + aux0[ei] * s);
                z1[ei]                     = f2bf(m + aux1[ei] * s);
                kls += -0.5f * (1.f + 2.f * l - m * m - expf(2.f * l));
            }
        }
#pragma unroll
        for (int off = 32; off >= 1; off >>= 1) kls += __shfl_xor(kls, off);
        __shared__ float redS[4];
        if (lane == 0) redS[wave] = kls;
        __syncthreads();
        if (threadIdx.x == 0) atomicAdd(accv, redS[0] + redS[1] + redS[2] + redS[3]);
        return;
    }

    float fsum = 0.f;
#pragma unroll
    for (int n0 = 0; n0 < 4; ++n0) {
        int col = col0 + n0 * 16 + frow;
        float bs = bias[col < Nreal ? col : Nreal - 1];
#pragma unroll
        for (int j = 0; j < 4; ++j) {
            float v = accs[n0][j] + bs;
            if (ACT == 1)      v = v > 0.f ? v : 0.f;
            else if (ACT == 2) v = v > 0.f ? v : 0.2f * v;
            else if (ACT == 3) v = 1.f / (1.f + expf(-v));
            if (MODE == 2) {
                if (col < Nreal) {
                    float d = v - aux0[(size_t)(orow + j) * 300 + col];
                    fsum += d * d;
                }
            } else {
                size_t idx = (size_t)(orow + j) * ldc + col;
                if (MODE == 1) ((float*)Cv)[idx] = v;
                else           ((short*)Cv)[idx] = f2bf(v);
            }
        }
    }
    if (MODE == 2) {
#pragma unroll
        for (int off = 32; off >= 1; off >>= 1) fsum += __shfl_xor(fsum, off);
        __shared__ float redF[4];
        if (lane == 0) redF[wave] = fsum;
        __syncthreads();
        if (threadIdx.x == 0) atomicAdd(accv, redF[0] + redF[1] + redF[2] + redF[3]);
    }
}

// ================= DISPATCH 2: persistent task pipeline =================
__device__ inline void wait_ge(unsigned* p, unsigned target)
{
    while (__hip_atomic_load(p, __ATOMIC_ACQUIRE, __HIP_MEMORY_SCOPE_AGENT) < target)
        __builtin_amdgcn_s_sleep(8);
}

__global__ __launch_bounds__(256, 2) void pipeline(Args g)
{
    __shared__ short As[64][72];
    __shared__ short Bs[64][72];

    for (int t = blockIdx.x; t < NTASK; t += PGRID) {
        // ---- wait on producers (thread 0 spins; syncthreads propagates) ----
        if (threadIdx.x == 0) {
            unsigned* f = nullptr; unsigned tg = 0;
            if      (t >= T_CSL)  { f = g.flg + (F_QZ2 + ((t - T_CSL) >> 4)) * 16;  tg = 8; }
            else if (t >= T_QZ2)  { f = g.flg + (F_QZ1 + ((t - T_QZ2) >> 3)) * 16;  tg = 8; }
            else if (t >= T_FC4)  { f = g.flg + (F_FC3 + ((t - T_FC4) / 5)) * 16;   tg = 5; }
            else if (t >= T_QZ1)  { f = g.flg + (F_MULS + ((t - T_QZ1) >> 3)) * 16; tg = 16; }
            else if (t >= T_FC3)  { f = g.flg + (F_MULS + ((t - T_FC3) / 5)) * 16;  tg = 16; }
            else if (t >= T_QI2)  { f = g.flg + (F_QI1 + ((t - T_QI2) >> 3)) * 16;  tg = 8; }
            else if (t >= T_MULS) { f = g.flg + (F_FC1 + ((t - T_MULS) >> 4)) * 16; tg = 5; }
            if (f) wait_ge(f, tg);
            if (t >= T_CSL) wait_ge(g.flg + F_QI2A * 16, 64);   // E complete
            __threadfence();
        }
        __syncthreads();

        // ---- execute ----
        unsigned* post = nullptr;
        if (t < T_QI1) {                 // fc1
            int s = t;
            gemm_core<1,0>(As, Bs, s % 5, s / 5, g.xcat, g.w_fc1t, g.fc1_b, nullptr,
                           g.h1, 300, 640, 320, nullptr, nullptr, nullptr, nullptr, nullptr);
            post = g.flg + (F_FC1 + s / 5) * 16;
        } else if (t < T_MULS) {         // qi1
            int s = t - T_QI1;
            gemm_core<2,0>(As, Bs, s & 7, s >> 3, g.Rb, g.w_qi1t, g.qi1_b, nullptr,
                           g.Ehb, 512, 320, 512, nullptr, nullptr, nullptr, nullptr, nullptr);
            post = g.flg + (F_QI1 + (s >> 3)) * 16;
        } else if (t < T_QI2) {          // mu/ls + sample fuse
            int s = t - T_MULS;
            gemm_core<0,3>(As, Bs, s & 15, s >> 4, g.h1, g.w_mulst, g.mu_b, g.ls_b,
                           nullptr, 1024, 320, 0, g.eps1, g.eps2, g.zcat, g.zb, g.acc + 0);
            post = g.flg + (F_MULS + (s >> 4)) * 16;
        } else if (t < T_FC3) {          // qi2 -> E
            int s = t - T_QI2;
            gemm_core<2,1>(As, Bs, s & 7, s >> 3, g.Ehb, g.w_qi2t, g.qi2_b, nullptr,
                           g.E, 512, 512, 512, nullptr, nullptr, nullptr, nullptr, nullptr);
            post = g.flg + F_QI2A * 16;
        } else if (t < T_QZ1) {          // fc3
            int s = t - T_FC3;
            gemm_core<1,0>(As, Bs, s % 5, s / 5, g.zcat, g.w_fc3t, g.fc3_b, nullptr,
                           g.h3, 300, 832, 320, nullptr, nullptr, nullptr, nullptr, nullptr);
            post = g.flg + (F_FC3 + s / 5) * 16;
        } else if (t < T_FC4) {          // qz1
            int s = t - T_QZ1;
            gemm_core<2,0>(As, Bs, s & 7, s >> 3, g.zb, g.w_qz1t, g.qz1_b, nullptr,
                           g.t1, 512, 512, 512, nullptr, nullptr, nullptr, nullptr, nullptr);
            post = g.flg + (F_QZ1 + (s >> 3)) * 16;
        } else if (t < T_QZ2) {          // fc4 + recon fuse
            int s = t - T_FC4;
            gemm_core<3,2>(As, Bs, s % 5, s / 5, g.h3, g.w_fc4t, g.fc4_b, nullptr,
                           nullptr, 300, 320, 0, g.xf, nullptr, nullptr, nullptr, g.acc + 1);
            post = nullptr;              // nothing consumes recon
        } else if (t < T_CSL) {          // qz2 -> zp
            int s = t - T_QZ2;
            gemm_core<2,1>(As, Bs, s & 7, s >> 3, g.t1, g.w_qz2t, g.qz2_b, nullptr,
                           g.zp, 512, 512, 512, nullptr, nullptr, nullptr, nullptr, nullptr);
            post = g.flg + (F_QZ2 + (s >> 3)) * 16;
        } else {                         // csl (4 rows)
            int s = t - T_CSL;
            int lane = threadIdx.x & 63;
            int wv   = threadIdx.x >> 6;
            int r    = s * 4 + wv;
            const float* z = g.zp + (size_t)r * LAT;
            const float4 za = reinterpret_cast<const float4*>(z)[lane * 2 + 0];
            const float4 zb = reinterpret_cast<const float4*>(z)[lane * 2 + 1];
            int ids[21];
            ids[0] = g.top_idx[r];
#pragma unroll
            for (int n = 0; n < 20; ++n) ids[n + 1] = g.dis_idx[r * 20 + n];
            float lg[21];
#pragma unroll
            for (int q = 0; q < 21; ++q) {
                const float* e = g.E + (size_t)ids[q] * LAT;
                const float4 ea = reinterpret_cast<const float4*>(e)[lane * 2 + 0];
                const float4 eb = reinterpret_cast<const float4*>(e)[lane * 2 + 1];
                float d = za.x * ea.x + za.y * ea.y + za.z * ea.z + za.w * ea.w
                        + zb.x * eb.x + zb.y * eb.y + zb.z * eb.z + zb.w * eb.w;
#pragma unroll
                for (int off = 32; off >= 1; off >>= 1) d += __shfl_xor(d, off);
                lg[q] = d / 0.07f;
            }
            float m = lg[0];
#pragma unroll
            for (int q = 1; q < 21; ++q) m = fmaxf(m, lg[q]);
            float ssum = 0.f;
#pragma unroll
            for (int q = 0; q < 21; ++q) ssum += expf(lg[q] - m);
            float loss = logf(ssum) + m - lg[0];
            __shared__ float redC[4];
            if (lane == 0) redC[wv] = loss;
            __syncthreads();
            if (threadIdx.x == 0) {
                atomicAdd(&g.acc[2], redC[0] + redC[1] + redC[2] + redC[3]);
                __threadfence();
                unsigned old = atomicAdd(g.flg + F_CSLD * 16, 1u);
                if (old == 511u) {
                    __threadfence();
                    volatile float* va = g.acc;
                    g.out[0] = va[0] + va[1];   // kl + recon
                    g.out[1] = va[2];           // csl
                }
            }
        }

        // ---- publish ----
        __syncthreads();
        if (threadIdx.x == 0 && post) {
            __threadfence();
            __hip_atomic_fetch_add(post, 1u, __ATOMIC_RELEASE, __HIP_MEMORY_SCOPE_AGENT);
        }
    }
}

// ================= launcher =================
extern "C" void kernel_launch(void* const* d_in, const int* in_sizes, int n_in,
                              void* d_out, int out_size, void* d_ws, size_t ws_size,
                              hipStream_t stream)
{
    const float* logits   = (const float*)d_in[0];
    const int*   rels     = (const int*)  d_in[1];
    const float* rel_dict = (const float*)d_in[2];
    const float* fc1_w    = (const float*)d_in[3];
    const float* fc1_b    = (const float*)d_in[4];
    const float* fc2mu_w  = (const float*)d_in[5];
    const float* fc2mu_b  = (const float*)d_in[6];
    const float* fc2ls_w  = (const float*)d_in[7];
    const float* fc2ls_b  = (const float*)d_in[8];
    const float* fc3_w    = (const float*)d_in[9];
    const float* fc3_b    = (const float*)d_in[10];
    const float* fc4_w    = (const float*)d_in[11];
    const float* fc4_b    = (const float*)d_in[12];
    const float* qi1_w    = (const float*)d_in[13];
    const float* qi1_b    = (const float*)d_in[14];
    const float* qi2_w    = (const float*)d_in[15];
    const float* qi2_b    = (const float*)d_in[16];
    const float* qz1_w    = (const float*)d_in[17];
    const float* qz1_b    = (const float*)d_in[18];
    const float* qz2_w    = (const float*)d_in[19];
    const float* qz2_b    = (const float*)d_in[20];
    const float* eps1     = (const float*)d_in[21];
    const float* eps2     = (const float*)d_in[22];
    float* out = (float*)d_out;

    char* wsb = (char*)d_ws;
    size_t off = 0;
    auto alloc = [&](size_t bytes) -> void* {
        off = (off + 255) & ~(size_t)255;
        void* p = wsb + off;
        off += bytes;
        return p;
    };
    float*    acc = (float*)alloc(256);
    unsigned* flg = (unsigned*)alloc(NFLAGW * 4);
    int*   top_idx = (int*)  alloc((size_t)B * 4);
    int*   dis_idx = (int*)  alloc((size_t)B * 20 * 4);
    short* Rb      = (short*)alloc((size_t)NRELS * 320 * 2);
    short* Ehb     = (short*)alloc((size_t)NRELS * 512 * 2);
    float* E       = (float*)alloc((size_t)NRELS * 512 * 4);
    short* xcat    = (short*)alloc((size_t)B * 640 * 2);
    float* xf      = (float*)alloc((size_t)B * 300 * 4);
    short* h1      = (short*)alloc((size_t)B * 320 * 2);
    short* zcat    = (short*)alloc((size_t)B * 832 * 2);
    short* zb      = (short*)alloc((size_t)B * 512 * 2);
    short* h3      = (short*)alloc((size_t)B * 320 * 2);
    short* t1      = (short*)alloc((size_t)B * 512 * 2);

    short* w_qi1t  = (short*)alloc((size_t)512 * 320 * 2);
    short* w_qi2t  = (short*)alloc((size_t)512 * 512 * 2);
    short* w_fc1t  = (short*)alloc((size_t)320 * 640 * 2);
    short* w_mulst = (short*)alloc((size_t)1024 * 320 * 2);  // interleaved mu/ls
    short* w_fc3t  = (short*)alloc((size_t)320 * 832 * 2);
    short* w_fc4t  = (short*)alloc((size_t)320 * 320 * 2);
    short* w_qz1t  = (short*)alloc((size_t)512 * 512 * 2);
    short* w_qz2t  = (short*)alloc((size_t)512 * 512 * 2);

    Args g;
    g.logits = logits; g.rels = rels; g.rel_dict = rel_dict;
    g.fc1_b = fc1_b; g.mu_b = fc2mu_b; g.ls_b = fc2ls_b;
    g.fc3_b = fc3_b; g.fc4_b = fc4_b;
    g.qi1_b = qi1_b; g.qi2_b = qi2_b; g.qz1_b = qz1_b; g.qz2_b = qz2_b;
    g.eps1 = eps1; g.eps2 = eps2;
    g.out = out; g.zp = out + 2 + 512;
    g.acc = acc; g.flg = flg;
    g.top_idx = top_idx; g.dis_idx = dis_idx;
    g.Rb = Rb; g.Ehb = Ehb; g.E = E;
    g.xcat = xcat; g.xf = xf;
    g.h1 = h1; g.zcat = zcat; g.zb = zb; g.h3 = h3; g.t1 = t1;
    g.w_qi1t = w_qi1t; g.w_qi2t = w_qi2t; g.w_fc1t = w_fc1t; g.w_mulst = w_mulst;
    g.w_fc3t = w_fc3t; g.w_fc4t = w_fc4t; g.w_qz1t = w_qz1t; g.w_qz2t = w_qz2t;

    //           src      dst      K    N   Kpad  Npad ilv off tstart tk
    g.wp.d[0] = {qi1_w,   w_qi1t,  300, 512, 320,  512, 0, 0,    0,  5};   // 40
    g.wp.d[1] = {qi2_w,   w_qi2t,  512, 512, 512,  512, 0, 0,   40,  8};   // 64
    g.wp.d[2] = {fc1_w,   w_fc1t,  600, 300, 640,  320, 0, 0,  104, 10};   // 50
    g.wp.d[3] = {fc2mu_w, w_mulst, 300, 512, 320, 1024, 1, 0,  154,  5};   // 40
    g.wp.d[4] = {fc2ls_w, w_mulst, 300, 512, 320, 1024, 1, 32, 194,  5};   // 40
    g.wp.d[5] = {fc3_w,   w_fc3t,  812, 300, 832,  320, 0, 0,  234, 13};   // 65
    g.wp.d[6] = {fc4_w,   w_fc4t,  300, 300, 320,  320, 0, 0,  299,  5};   // 25
    g.wp.d[7] = {qz1_w,   w_qz1t,  512, 512, 512,  512, 0, 0,  324,  8};   // 64
    g.wp.d[8] = {qz2_w,   w_qz2t,  512, 512, 512,  512, 0, 0,  388,  8};   // 64 -> 452

    prep    <<<1093,  256, 0, stream>>>(g);
    pipeline<<<PGRID, 256, 0, stream>>>(g);
}